// Round 7
// baseline (95.189 us; speedup 1.0000x reference)
//
#include <hip/hip_runtime.h>
#include <math.h>

// Fused SSIM: separable 11x11 gaussian depthwise conv of {x1,x2,x1^2,x2^2,x1*x2},
// SSIM map, global mean -> scalar. NCHW (16,3,512,512) fp32, VALID -> 502x502.
//
// R7 = R6 (single-wave barrier-free blocks) + __launch_bounds__(64,2).
// R6 post-mortem: VGPR_Count=56 < ~80-reg live set with ZERO scratch traffic
// -> compiler shuffles accumulators through AGPRs (v_accvgpr_read/write, 3
// VALU per VTAP instead of 1) -> measured ~328 inst/wave-row vs ~160 ideal.
// Fix: raise the regalloc ceiling (cap 256), occupancy stays grid-limited at
// 3 waves/SIMD for VGPR<=170, so no R3-style downside.
//   R0 lesson: dynamic acc indices -> scratch spill.
//   R3 lesson: never cap VGPR below live set.
//   R5 lesson: 8 B LDS lane stride (float2) = conflict-free; 16 B = 8-way.
//   R6 lesson: barrier-free single-wave blocks raise VALUBusy 64->78%.

#define W 512
#define H 512
#define OWID 502            // output rows/cols (512-11+1)
#define NS 8                // row strips
#define SH 63               // output rows per strip
#define NCHUNK 8            // column chunks of 64
#define NPLANES 48          // 16*3
#define NBLOCKS (NPLANES * NCHUNK * NS)   // 3072 = 12 waves/CU exactly
#define NTOTAL 12096192.0   // 48*502*502

// gaussian(sigma=1.5, ws=11), normalized; compile-time constants.
#define G0 0.00102838f
#define G1 0.00759860f
#define G2 0.03600090f
#define G3 0.10936100f
#define G4 0.21300540f
#define G5 0.26601170f
#define GW(K) (((K)==0||(K)==10) ? G0 : ((K)==1||(K)==9) ? G1 : \
               ((K)==2||(K)==8)  ? G2 : ((K)==3||(K)==7) ? G3 : \
               ((K)==4||(K)==6)  ? G4 : G5)

// vertical tap: slot index is a constant expression (P,D are literals)
#define VTAP(P,D) { \
    constexpr int s_ = (((P) - (D)) % 11 + 11) % 11; \
    const float wv_ = GW(D); \
    acc1[s_]  = fmaf(wv_, h1,  acc1[s_]); \
    acc2[s_]  = fmaf(wv_, h2,  acc2[s_]); \
    acc11[s_] = fmaf(wv_, h11, acc11[s_]); \
    acc22[s_] = fmaf(wv_, h22, acc22[s_]); \
    acc12[s_] = fmaf(wv_, h12, acc12[s_]); }

#define PHASE(P) if (ir < ir_end) { \
    float2* sb_ = sbuf[ir & 1]; \
    sb_[tid] = make_float2(ra, rb);        /* main col */ \
    if (tid < 10) sb_[64 + tid] = make_float2(rc, rd);   /* halo */ \
    asm volatile("" ::: "memory");         /* pin write->read program order */ \
    { const size_t nro_ = (size_t)min(ir + 1, H - 1) * W; \
      ra = p1[nro_ + col_main]; rb = p2[nro_ + col_main]; \
      if (tid < 10) { rc = p1[nro_ + col_halo]; rd = p2[nro_ + col_halo]; } } \
    float h1 = 0.f, h2 = 0.f, h11 = 0.f, h22 = 0.f, h12 = 0.f; \
    _Pragma("unroll") \
    for (int k = 0; k < 11; ++k) { \
        float2 v_ = sb_[tid + k]; \
        const float wk_ = GW(k); \
        float wa_ = wk_ * v_.x, wb_ = wk_ * v_.y; \
        h1 += wa_; h2 += wb_; \
        h11 = fmaf(wa_, v_.x, h11); \
        h22 = fmaf(wb_, v_.y, h22); \
        h12 = fmaf(wa_, v_.y, h12); } \
    VTAP(P,0) VTAP(P,1) VTAP(P,2) VTAP(P,3) VTAP(P,4) VTAP(P,5) \
    VTAP(P,6) VTAP(P,7) VTAP(P,8) VTAP(P,9) VTAP(P,10) \
    { constexpr int cs_ = ((P) + 1) % 11; \
      const int orow_ = ir - 10; \
      if (orow_ >= r0 && orow_ < r1) { \
          float mu1_ = acc1[cs_], mu2_ = acc2[cs_]; \
          float m1s_ = mu1_ * mu1_, m2s_ = mu2_ * mu2_, m12_ = mu1_ * mu2_; \
          float s11_ = acc11[cs_] - m1s_; \
          float s22_ = acc22[cs_] - m2s_; \
          float s12_ = acc12[cs_] - m12_; \
          float num_ = (2.f * m12_ + C1) * (2.f * s12_ + C2); \
          float den_ = (m1s_ + m2s_ + C1) * (s11_ + s22_ + C2); \
          sum += colok ? (num_ / den_) : 0.f; } \
      acc1[cs_] = 0.f; acc2[cs_] = 0.f; acc11[cs_] = 0.f; \
      acc22[cs_] = 0.f; acc12[cs_] = 0.f; } \
    ++ir; }

__global__ __launch_bounds__(64, 2)
void ssim_main(const float* __restrict__ img1, const float* __restrict__ img2,
               double* __restrict__ partials)
{
    __shared__ float2 sbuf[2][128];   // ping-pong staged row (x1,x2); 2 KiB

    const int tid   = threadIdx.x;    // = lane (single-wave block)
    const int bid   = blockIdx.x;
    const int chunk = bid % NCHUNK;
    const int strip = (bid / NCHUNK) % NS;
    const int plane = bid / (NCHUNK * NS);

    const int c0 = chunk * 64;
    const int r0 = strip * SH;
    const int nrows = min(SH, OWID - r0);
    const int r1 = r0 + nrows;
    const int ir_end = r0 + nrows + 10;          // exact rows needed
    const int ngroups = (nrows + 20) / 11;

    const size_t pbase = (size_t)plane * (W * H);
    const float* __restrict__ p1 = img1 + pbase;
    const float* __restrict__ p2 = img2 + pbase;

    const int col_main = c0 + tid;                       // <= 511 always
    const int col_halo = min(c0 + 64 + tid, W - 1);      // clamped; [64..73] used
    const bool colok = (c0 + tid) < OWID;

    const float C1 = 4.0e-4f;    // (0.01*2)^2
    const float C2 = 3.6e-3f;    // (0.03*2)^2

    // rotating 11-slot accumulators (all indices parse-time constants)
    float acc1[11], acc2[11], acc11[11], acc22[11], acc12[11];
#pragma unroll
    for (int i = 0; i < 11; ++i) {
        acc1[i] = 0.f; acc2[i] = 0.f; acc11[i] = 0.f; acc22[i] = 0.f; acc12[i] = 0.f;
    }

    float sum = 0.f;
    int ir = r0;

    // prefetch first row
    float ra, rb, rc = 0.f, rd = 0.f;
    {
        const size_t ro = (size_t)ir * W;
        ra = p1[ro + col_main]; rb = p2[ro + col_main];
        if (tid < 10) { rc = p1[ro + col_halo]; rd = p2[ro + col_halo]; }
    }

    for (int g = 0; g < ngroups; ++g) {
        PHASE(0) PHASE(1) PHASE(2) PHASE(3) PHASE(4) PHASE(5)
        PHASE(6) PHASE(7) PHASE(8) PHASE(9) PHASE(10)
    }

    // wave reduction (single wave): shfl tree -> lane 0
#pragma unroll
    for (int off = 32; off > 0; off >>= 1)
        sum += __shfl_down(sum, off, 64);
    if (tid == 0)
        partials[bid] = (double)sum;
}

__global__ void ssim_final(const double* __restrict__ partials, float* __restrict__ out)
{
    __shared__ double sd[256];
    const int tid = threadIdx.x;
    double s = 0.0;
    for (int i = tid; i < NBLOCKS; i += 256) s += partials[i];
    sd[tid] = s;
    __syncthreads();
    for (int off = 128; off > 0; off >>= 1) {
        if (tid < off) sd[tid] += sd[tid + off];
        __syncthreads();
    }
    if (tid == 0) out[0] = 1.0f - (float)(sd[0] / NTOTAL);
}

extern "C" void kernel_launch(void* const* d_in, const int* in_sizes, int n_in,
                              void* d_out, int out_size, void* d_ws, size_t ws_size,
                              hipStream_t stream)
{
    const float* img1 = (const float*)d_in[0];
    const float* img2 = (const float*)d_in[1];
    float* out = (float*)d_out;
    double* partials = (double*)d_ws;   // NBLOCKS doubles = 24576 B

    ssim_main<<<NBLOCKS, 64, 0, stream>>>(img1, img2, partials);
    ssim_final<<<1, 256, 0, stream>>>(partials, out);
}

// Round 8
// 70.357 us; speedup vs baseline: 1.3529x; 1.3529x over previous
//
#include <hip/hip_runtime.h>
#include <math.h>

// Fused SSIM: separable 11x11 gaussian depthwise conv of {x1,x2,x1^2,x2^2,x1*x2},
// SSIM map, global mean -> scalar. NCHW (16,3,512,512) fp32, VALID -> 502x502.
//
// R8: packed-FP32 (v_pk_*_f32) 2-rows-per-phase version of R6's single-wave
// barrier-free structure. MI355X's 157 TF fp32 = the PACKED pair rate; all
// prior rounds issued scalar FMAs (78.6 TF ceiling) and measured ~2x my
// hand-counted instruction budget. LDS stages row-PAIRS as (r0,r1) float2 so
// ds_read_b64 yields packed operands directly; rotating 11-slot accumulators
// become packed pairs (weights (G[d],G[d+1])); all slot indices parse-time
// constants (R0 lesson). Halo unconditional (R7 lesson: divergent guards
// regressed). Single LDS buffer: DS ops within one wave execute in order;
// asm memory clobbers pin program order (no barriers anywhere).
//   R3 lesson: never cap VGPR below live set -> launch_bounds(64,2), ~150 live.
//   R5 lesson: 8 B LDS lane stride = conflict-free.

typedef float f32x2 __attribute__((ext_vector_type(2)));

#define W 512
#define H 512
#define OWID 502            // output rows/cols (512-11+1)
#define NS 8                // row strips
#define SH 63               // output rows per strip
#define NCHUNK 8            // column chunks of 64
#define NPLANES 48          // 16*3
#define NBLOCKS (NPLANES * NCHUNK * NS)   // 3072 = 12 waves/CU
#define NTOTAL 12096192.0   // 48*502*502

// gaussian(sigma=1.5, ws=11), normalized; compile-time constants.
#define G0 0.00102838f
#define G1 0.00759860f
#define G2 0.03600090f
#define G3 0.10936100f
#define G4 0.21300540f
#define G5 0.26601170f
#define GW(K) (((K)==0||(K)==10) ? G0 : ((K)==1||(K)==9) ? G1 : \
               ((K)==2||(K)==8)  ? G2 : ((K)==3||(K)==7) ? G3 : \
               ((K)==4||(K)==6)  ? G4 : G5)
#define GWX(K) (((K) >= 11) ? 0.f : GW(K))

__device__ __forceinline__ f32x2 pk_fma(f32x2 a, f32x2 b, f32x2 c) {
    f32x2 d; asm("v_pk_fma_f32 %0, %1, %2, %3" : "=v"(d) : "v"(a), "v"(b), "v"(c)); return d;
}
__device__ __forceinline__ f32x2 pk_mul(f32x2 a, f32x2 b) {
    f32x2 d; asm("v_pk_mul_f32 %0, %1, %2" : "=v"(d) : "v"(a), "v"(b)); return d;
}
__device__ __forceinline__ f32x2 pk_add(f32x2 a, f32x2 b) {
    f32x2 d; asm("v_pk_add_f32 %0, %1, %2" : "=v"(d) : "v"(a), "v"(b)); return d;
}

// vertical packed tap: phase rows (ra=ir, rb=ir+1); D = ra - or.
// acc[slot(or)] += (G[D]*h.x, G[D+1]*h.y); slot relative to r0.
#define VTAP2(PP,D) { \
    constexpr int s_ = (((2*(PP) - (D)) % 11) + 11) % 11; \
    const f32x2 wv_ = {GW(D), GWX((D)+1)}; \
    acc1[s_]  = pk_fma(wv_, h1,  acc1[s_]); \
    acc2[s_]  = pk_fma(wv_, h2,  acc2[s_]); \
    acc11[s_] = pk_fma(wv_, h11, acc11[s_]); \
    acc22[s_] = pk_fma(wv_, h22, acc22[s_]); \
    acc12[s_] = pk_fma(wv_, h12, acc12[s_]); }

#define CONSUME(S, OROK) if (OROK) { \
    const float mu1_ = acc1[S].x + acc1[S].y; \
    const float mu2_ = acc2[S].x + acc2[S].y; \
    const float e11_ = acc11[S].x + acc11[S].y; \
    const float e22_ = acc22[S].x + acc22[S].y; \
    const float e12_ = acc12[S].x + acc12[S].y; \
    const float m1s_ = mu1_*mu1_, m2s_ = mu2_*mu2_, m12_ = mu1_*mu2_; \
    const float s11_ = e11_ - m1s_, s22_ = e22_ - m2s_, s12_ = e12_ - m12_; \
    const float num_ = (2.f*m12_ + C1) * (2.f*s12_ + C2); \
    const float den_ = (m1s_ + m2s_ + C1) * (s11_ + s22_ + C2); \
    sum += colok ? num_ * __builtin_amdgcn_rcpf(den_) : 0.f; }

#define PHASE2(PP) if (ir < ir_end) { \
    asm volatile("" ::: "memory"); \
    sA[tid]      = (f32x2){ra0, ra1}; \
    sB[tid]      = (f32x2){rb0, rb1}; \
    sA[64 + tid] = (f32x2){rc0, rc1}; \
    sB[64 + tid] = (f32x2){rd0, rd1}; \
    asm volatile("" ::: "memory"); \
    { const size_t m0_ = (size_t)min(ir + 2, H - 1) * W; \
      const size_t m1_ = (size_t)min(ir + 3, H - 1) * W; \
      ra0 = p1[m0_ + col_main]; ra1 = p1[m1_ + col_main]; \
      rb0 = p2[m0_ + col_main]; rb1 = p2[m1_ + col_main]; \
      rc0 = p1[m0_ + col_halo]; rc1 = p1[m1_ + col_halo]; \
      rd0 = p2[m0_ + col_halo]; rd1 = p2[m1_ + col_halo]; } \
    f32x2 h1, h2, h11, h22, h12; \
    _Pragma("unroll") \
    for (int k = 0; k < 11; ++k) { \
        const f32x2 wk_ = {GW(k), GW(k)}; \
        const f32x2 va_ = sA[tid + k]; \
        const f32x2 vb_ = sB[tid + k]; \
        const f32x2 wa_ = pk_mul(wk_, va_); \
        const f32x2 wb_ = pk_mul(wk_, vb_); \
        if (k == 0) { \
            h1 = wa_; h2 = wb_; \
            h11 = pk_mul(wa_, va_); h22 = pk_mul(wb_, vb_); h12 = pk_mul(wa_, vb_); \
        } else { \
            h1 = pk_add(h1, wa_); h2 = pk_add(h2, wb_); \
            h11 = pk_fma(wa_, va_, h11); h22 = pk_fma(wb_, vb_, h22); \
            h12 = pk_fma(wa_, vb_, h12); } } \
    VTAP2(PP,0) VTAP2(PP,1) VTAP2(PP,2) VTAP2(PP,3) VTAP2(PP,4) VTAP2(PP,5) \
    VTAP2(PP,6) VTAP2(PP,7) VTAP2(PP,8) VTAP2(PP,9) VTAP2(PP,10) \
    { constexpr int sa_ = (2*(PP) + 1) % 11;   /* slot of or_a = ir-10; reused by new row rb */ \
      constexpr int sb_ = (2*(PP) + 2) % 11;   /* slot of or_b = ir-9; reused by row ir+2     */ \
      const int orA_ = ir - 10, orB_ = ir - 9; \
      CONSUME(sa_, (orA_ >= r0 && orA_ < r1)) \
      CONSUME(sb_, (orB_ >= r0 && orB_ < r1)) \
      const f32x2 wg0_ = {0.f, G0}; \
      acc1[sa_]  = pk_mul(wg0_, h1);   /* restart slot with rb's tap D'=0 */ \
      acc2[sa_]  = pk_mul(wg0_, h2); \
      acc11[sa_] = pk_mul(wg0_, h11); \
      acc22[sa_] = pk_mul(wg0_, h22); \
      acc12[sa_] = pk_mul(wg0_, h12); \
      acc1[sb_] = zz; acc2[sb_] = zz; acc11[sb_] = zz; acc22[sb_] = zz; acc12[sb_] = zz; } \
    ir += 2; }

__global__ __launch_bounds__(64, 2)
void ssim_main(const float* __restrict__ img1, const float* __restrict__ img2,
               double* __restrict__ partials)
{
    __shared__ f32x2 sA[128];   // (x1[row_even], x1[row_odd]) per col; 64 main + halo
    __shared__ f32x2 sB[128];   // x2 pairs

    const int tid   = threadIdx.x;    // = lane (single-wave block)
    const int bid   = blockIdx.x;
    const int chunk = bid % NCHUNK;
    const int strip = (bid / NCHUNK) % NS;
    const int plane = bid / (NCHUNK * NS);

    const int c0 = chunk * 64;
    const int r0 = strip * SH;
    const int nrows = min(SH, OWID - r0);
    const int r1 = r0 + nrows;
    const int ir_end = r0 + nrows + 10;   // last needed input row + 1

    const size_t pbase = (size_t)plane * (W * H);
    const float* __restrict__ p1 = img1 + pbase;
    const float* __restrict__ p2 = img2 + pbase;

    const int col_main = c0 + tid;                       // <= 511 always
    const int col_halo = min(c0 + 64 + tid, W - 1);      // clamped; [64..73] used
    const bool colok = (c0 + tid) < OWID;

    const float C1 = 4.0e-4f;    // (0.01*2)^2
    const float C2 = 3.6e-3f;    // (0.03*2)^2
    const f32x2 zz = {0.f, 0.f};

    // rotating 11-slot packed accumulators (indices all parse-time constants)
    f32x2 acc1[11], acc2[11], acc11[11], acc22[11], acc12[11];
#pragma unroll
    for (int i = 0; i < 11; ++i) {
        acc1[i]=zz; acc2[i]=zz; acc11[i]=zz; acc22[i]=zz; acc12[i]=zz;
    }

    float sum = 0.f;
    int ir = r0;

    // prefetch first row pair (rows r0, r0+1)
    float ra0, ra1, rb0, rb1, rc0, rc1, rd0, rd1;
    {
        const size_t m0 = (size_t)ir * W;
        const size_t m1 = (size_t)(ir + 1) * W;
        ra0 = p1[m0 + col_main]; ra1 = p1[m1 + col_main];
        rb0 = p2[m0 + col_main]; rb1 = p2[m1 + col_main];
        rc0 = p1[m0 + col_halo]; rc1 = p1[m1 + col_halo];
        rd0 = p2[m0 + col_halo]; rd1 = p2[m1 + col_halo];
    }

    // 11 phases cover 22 rows (period of slot-rotation x row-parity); 4 groups
    // = up to 44 phases = 88 rows, guard trims to the 71-74 actually needed.
#pragma unroll 1
    for (int g = 0; g < 4; ++g) {
        PHASE2(0) PHASE2(1) PHASE2(2) PHASE2(3) PHASE2(4) PHASE2(5)
        PHASE2(6) PHASE2(7) PHASE2(8) PHASE2(9) PHASE2(10)
    }

    // wave reduction (single wave): shfl tree -> lane 0
#pragma unroll
    for (int off = 32; off > 0; off >>= 1)
        sum += __shfl_down(sum, off, 64);
    if (tid == 0)
        partials[bid] = (double)sum;
}

__global__ void ssim_final(const double* __restrict__ partials, float* __restrict__ out)
{
    __shared__ double sd[256];
    const int tid = threadIdx.x;
    double s = 0.0;
    for (int i = tid; i < NBLOCKS; i += 256) s += partials[i];
    sd[tid] = s;
    __syncthreads();
    for (int off = 128; off > 0; off >>= 1) {
        if (tid < off) sd[tid] += sd[tid + off];
        __syncthreads();
    }
    if (tid == 0) out[0] = 1.0f - (float)(sd[0] / NTOTAL);
}

extern "C" void kernel_launch(void* const* d_in, const int* in_sizes, int n_in,
                              void* d_out, int out_size, void* d_ws, size_t ws_size,
                              hipStream_t stream)
{
    const float* img1 = (const float*)d_in[0];
    const float* img2 = (const float*)d_in[1];
    float* out = (float*)d_out;
    double* partials = (double*)d_ws;   // NBLOCKS doubles = 24576 B

    ssim_main<<<NBLOCKS, 64, 0, stream>>>(img1, img2, partials);
    ssim_final<<<1, 256, 0, stream>>>(partials, out);
}